// Round 10
// baseline (382.377 us; speedup 1.0000x reference)
//
#include <hip/hip_runtime.h>
#include <hip/hip_bf16.h>

#define N_NODES   50000
#define N_PAD     50048                 // ceil64
#define N_EDGES   800000
#define N_REL     16
#define N_GRAPHS  64
#define DIM       128
#define FC_DIM    256
#define N_CLASSES 16

#define SB        50176                 // src bins per rel (49*1024)
#define NBINS_P   (16 * SB)             // 802816
#define NBLK_PP   784
#define NCOARSE   782                   // dst>>6 bins
#define NCH       392                   // edge chunks
#define CHSZ      2048
// virtual blocks for phase A: fixed internal sweep chunking (independent of NCH)
#define NBVIRT    13328
#define VB_SPLIT  6664                  // phaseA1 split across the two fused launches
#define PA_BLK    1024                  // phaseA resident blocks per launch

#define NBLK_CX   27200                 // XW_TOTAL/256
#define XW_TOTAL  (N_PAD * DIM + 2 * 17 * 16384)

// ---- ws layout (bytes, 256-aligned) ----
#define WS_MARK   0                     // 802816  } contiguous
#define WS_HG     802816                // 32768   } memset
#define WS_CNT    835584                // 256     } region (hole, unused)
#define WS_SRCOF  835840                // 3203072 } (pads must be 0)
#define MEMSET_SZ 4038912
#define WS_BLKH   4038912               // 392*782*4 = 1226176 -> 1226240
#define WS_COFS   5265152               // 3328
#define WS_PARTP  5268480               // 3328
#define WS_BLKB   5271808               // 3328
#define WS_RELB   5275136               // 256
#define WS_CIDMAP 5275392               // 3211264
#define WS_RTMP   8486656               // 3200000
#define WS_RECS   11686656              // 3200000
#define WS_OFFSD  14886656              // 200448
#define WS_X1     15087104              // 12812288
#define WS_X2     27899392              // 12812288
#define WS_WB     40711680              // 1114112
#define WS_T      41825792              // + rows*256B (actual ~143MB)

typedef __attribute__((ext_vector_type(8))) short bf16x8;
typedef __attribute__((ext_vector_type(4))) float f32x4;

__device__ __forceinline__ void atomAddF(float* p, float v) {
#if defined(__gfx90a__) || defined(__gfx942__) || defined(__gfx950__)
    unsafeAtomicAdd(p, v);
#else
    atomicAdd(p, v);
#endif
}

__device__ __forceinline__ float bf2f(unsigned int u) {
    union { float f; unsigned int i; } x; x.i = u << 16; return x.f;
}
__device__ __forceinline__ unsigned short f2bf(float f) {
    union { float f; unsigned int u; } x; x.f = f;
    unsigned int r = x.u + 0x7fff + ((x.u >> 16) & 1);
    return (unsigned short)(r >> 16);
}
__device__ __forceinline__ void accum8(float* qa, uint4 u) {
    qa[0] += bf2f(u.x & 0xffff); qa[1] += bf2f(u.x >> 16);
    qa[2] += bf2f(u.y & 0xffff); qa[3] += bf2f(u.y >> 16);
    qa[4] += bf2f(u.z & 0xffff); qa[5] += bf2f(u.z >> 16);
    qa[6] += bf2f(u.w & 0xffff); qa[7] += bf2f(u.w >> 16);
}
__device__ __forceinline__ void pack16(const float* qa, unsigned short* dst) {
    #pragma unroll
    for (int j = 0; j < 2; ++j) {
        uint4 w;
        w.x = ((unsigned int)f2bf(qa[j*8+1]) << 16) | f2bf(qa[j*8+0]);
        w.y = ((unsigned int)f2bf(qa[j*8+3]) << 16) | f2bf(qa[j*8+2]);
        w.z = ((unsigned int)f2bf(qa[j*8+5]) << 16) | f2bf(qa[j*8+4]);
        w.w = ((unsigned int)f2bf(qa[j*8+7]) << 16) | f2bf(qa[j*8+6]);
        ((uint4*)dst)[j] = w;
    }
}

// ---- fused: h1 (blocks 0..391, runs first) + convXW (blocks 392..) ----
__global__ __launch_bounds__(256) void k_h1cx(
    const int* __restrict__ src, const int* __restrict__ dst, const int* __restrict__ rel,
    unsigned char* __restrict__ mark, int* __restrict__ blockHist,
    const float* __restrict__ h, unsigned short* __restrict__ x1,
    const float* __restrict__ W1, const float* __restrict__ Ws1,
    const float* __restrict__ W2, const float* __restrict__ Ws2,
    unsigned short* __restrict__ Wb)
{
    __shared__ int hl[NCOARSE];
    int t = threadIdx.x;
    if (blockIdx.x < NCH) {
        int b = blockIdx.x;
        for (int i = t; i < NCOARSE; i += 256) hl[i] = 0;
        __syncthreads();
        int e0 = b * CHSZ;
        int eend = min(e0 + CHSZ, N_EDGES);
        for (int e = e0 + t; e < eend; e += 256) {
            int d = dst[e];
            mark[rel[e] * SB + src[e]] = 1;
            atomicAdd(&hl[d >> 6], 1);                   // LDS atomic
        }
        __syncthreads();
        for (int i = t; i < NCOARSE; i += 256) blockHist[b * NCOARSE + i] = hl[i];
    } else {
        int id = (blockIdx.x - NCH) * 256 + t;
        if (id < N_PAD * DIM) {
            int v = id >> 7;
            x1[id] = (v < N_NODES) ? f2bf(h[id]) : (unsigned short)0;
        } else {
            int tt = id - N_PAD * DIM;
            int l = tt / 278528, rem = tt % 278528;
            int r = rem >> 14, rr = rem & 16383;
            int n = rr >> 7, k = rr & 127;
            const float* W  = l ? W2 : W1;
            const float* Ws = l ? Ws2 : Ws1;
            float v = (r < 16) ? W[r * 16384 + k * 128 + n] : Ws[k * 128 + n];
            Wb[tt] = f2bf(v);
        }
    }
}

// ---- fused: scanPA (blocks 0..783) + per-bin chunk scan (blocks 784..1565).
__global__ __launch_bounds__(256) void k_sA(
    const unsigned int* __restrict__ markU, int* __restrict__ partP,
    int* __restrict__ blockHist, int* __restrict__ cOffs)
{
    int t = threadIdx.x;
    if (blockIdx.x < NBLK_PP) {
        __shared__ int red[256];
        int b = blockIdx.x;
        unsigned int u = markU[b * 256 + t];
        red[t] = (int)((u & 1) + ((u >> 8) & 1) + ((u >> 16) & 1) + ((u >> 24) & 1));
        __syncthreads();
        for (int o = 128; o > 0; o >>= 1) {
            if (t < o) red[t] += red[t + o];
            __syncthreads();
        }
        if (t == 0) partP[b] = red[0];
    } else {
        __shared__ int sc[2][256];
        int i = blockIdx.x - NBLK_PP;                    // 0..781
        int j0 = 2 * t, j1 = 2 * t + 1;
        int v0 = (j0 < NCH) ? blockHist[j0 * NCOARSE + i] : 0;
        int v1 = (j1 < NCH) ? blockHist[j1 * NCOARSE + i] : 0;
        int p = v0 + v1;
        sc[0][t] = p; __syncthreads();
        int cur = 0;
        for (int o = 1; o < 256; o <<= 1) {
            sc[cur ^ 1][t] = sc[cur][t] + ((t >= o) ? sc[cur][t - o] : 0);
            __syncthreads();
            cur ^= 1;
        }
        int excl = sc[cur][t] - p;                       // exclusive, no base
        if (j0 < NCH) blockHist[j0 * NCOARSE + i] = excl;
        if (j1 < NCH) blockHist[j1 * NCOARSE + i] = excl + v0;
        if (t == 255) cOffs[i] = sc[cur][255];           // bin total
    }
}

// ---- fused: scanPB (block 0) + cscanB (block 1) ----
__global__ __launch_bounds__(1024) void k_sB(
    const int* __restrict__ partP, int* __restrict__ blkB, int* __restrict__ relB,
    int* __restrict__ cOffs)
{
    int t = threadIdx.x;
    if (blockIdx.x == 0) {
        __shared__ int s1[784], s2[784];
        __shared__ int tot[16], rbase[17];
        int rel = t / 49, pos = t - rel * 49;
        int v = (t < 784) ? partP[t] : 0;
        if (t < 784) s1[t] = v;
        __syncthreads();
        int* cur = s1; int* nxt = s2;
        for (int o = 1; o < 64; o <<= 1) {
            if (t < 784) nxt[t] = cur[t] + ((pos >= o) ? cur[t - o] : 0);
            __syncthreads();
            int* tmp = cur; cur = nxt; nxt = tmp;
        }
        if (t < 784 && pos == 48) tot[rel] = cur[t];
        __syncthreads();
        if (t == 0) {
            int base = 0;
            for (int r = 0; r < 16; ++r) { rbase[r] = base; base += (tot[r] + 63) & ~63; }
            rbase[16] = base;
        }
        __syncthreads();
        if (t < 784) blkB[t] = rbase[rel] + cur[t] - v;
        if (t < 17)  relB[t] = rbase[t];
    } else {
        __shared__ int c1[1024], c2[1024];
        int v = (t < NCOARSE) ? cOffs[t] : 0;
        c1[t] = v; __syncthreads();
        int* cur = c1; int* nxt = c2;
        for (int o = 1; o < 1024; o <<= 1) {
            nxt[t] = cur[t] + ((t >= o) ? cur[t - o] : 0);
            __syncthreads();
            int* tmp = cur; cur = nxt; nxt = tmp;
        }
        if (t < NCOARSE) cOffs[t] = cur[t] - v;          // exclusive base
        if (t == NCOARSE) cOffs[NCOARSE] = cur[NCOARSE - 1];
    }
}

__global__ void k_scanPC(const unsigned int* __restrict__ markU, const int* __restrict__ blkB,
                         int* __restrict__ cidMap, int* __restrict__ srcOf) {
    __shared__ int s1[256], s2[256];
    int b = blockIdx.x, t = threadIdx.x;
    unsigned int u = markU[b * 256 + t];
    int f0 = (int)(u & 1), f1 = (int)((u >> 8) & 1);
    int f2 = (int)((u >> 16) & 1), f3 = (int)((u >> 24) & 1);
    int sum = f0 + f1 + f2 + f3;
    s1[t] = sum; __syncthreads();
    int* cur = s1; int* nxt = s2;
    for (int o = 1; o < 256; o <<= 1) {
        nxt[t] = cur[t] + ((t >= o) ? cur[t - o] : 0);
        __syncthreads();
        int* tmp = cur; cur = nxt; nxt = tmp;
    }
    int cid = blkB[b] + cur[t] - sum;
    int rel = b / 49;
    int key0 = b * 1024 + t * 4;
    int srcBase = key0 - rel * SB;
    if (f0) { cidMap[key0]     = cid; srcOf[cid] = srcBase;     cid++; }
    if (f1) { cidMap[key0 + 1] = cid; srcOf[cid] = srcBase + 1; cid++; }
    if (f2) { cidMap[key0 + 2] = cid; srcOf[cid] = srcBase + 2; cid++; }
    if (f3) { cidMap[key0 + 3] = cid; srcOf[cid] = srcBase + 3; cid++; }
}

// ---- fused launch: aux blocks (scat1 OR p2) + phaseA tile range ----
// mode=1: blocks [0,auxN) run scat1 (write rtmp).
// mode=2: blocks [0,auxN) run p2 (rtmp -> recs/offsD).
// Blocks [auxN, auxN+PA_BLK): phaseA pipeline over vb in [vb0, vb1).
// scat1/p2 only feed phaseB, so they overlap phaseA here; the launch
// boundary between mode=1 and mode=2 gives the scat1->p2 sync for free.
__global__ __launch_bounds__(256) void k_fuseAP(
    const unsigned short* __restrict__ x, const unsigned short* __restrict__ Wb,
    const int* __restrict__ srcOf, const int* __restrict__ relB,
    unsigned short* __restrict__ T,
    const int* __restrict__ src, const int* __restrict__ dst, const int* __restrict__ rel,
    const int* __restrict__ cidMap, const int* __restrict__ blockHist,
    const int* __restrict__ cOffs, unsigned int* __restrict__ rtmp,
    unsigned int* __restrict__ recs, int* __restrict__ offsD,
    int mode, int auxN, int vb0, int vb1)
{
    __shared__ __attribute__((aligned(16))) unsigned short Xs[64 * 136];
    __shared__ __attribute__((aligned(16))) unsigned short Cs[64 * 136];
    __shared__ int sRB[17];

    int tid = threadIdx.x;

    if ((int)blockIdx.x < auxN) {
        if (mode == 1) {                 // ---- scat1 (verbatim r9 body) ----
            int* baseL = (int*)Xs;                       // 782 ints (6256B < 17408B)
            int* hl    = ((int*)Xs) + NCOARSE;
            int b = blockIdx.x;
            for (int i = tid; i < NCOARSE; i += 256) {
                baseL[i] = blockHist[b * NCOARSE + i] + cOffs[i];
                hl[i] = 0;
            }
            __syncthreads();
            int e0 = b * CHSZ;
            int eend = min(e0 + CHSZ, N_EDGES);
            for (int e = e0 + tid; e < eend; e += 256) {
                int d = dst[e];
                int cid = cidMap[rel[e] * SB + src[e]];
                int c = d >> 6;
                int rank = atomicAdd(&hl[c], 1);         // LDS atomic
                rtmp[baseL[c] + rank] = ((unsigned int)cid << 6) | (unsigned int)(d & 63);
            }
        } else {                          // ---- p2 (verbatim r9 body) ----
            int* cntL  = (int*)Xs;                       // 64
            int* exclL = ((int*)Xs) + 64;                // 65
            int* cur2  = ((int*)Xs) + 129;               // 64
            int i = blockIdx.x;
            int segB = cOffs[i], segE = cOffs[i + 1];
            if (tid < 64) { cntL[tid] = 0; cur2[tid] = 0; }
            __syncthreads();
            for (int e = segB + tid; e < segE; e += 256)
                atomicAdd(&cntL[rtmp[e] & 63u], 1);
            __syncthreads();
            if (tid == 0) {
                int run = segB;
                #pragma unroll
                for (int d = 0; d < 64; ++d) { exclL[d] = run; run += cntL[d]; }
                exclL[64] = run;
            }
            __syncthreads();
            if (tid < 64) offsD[i * 64 + tid] = exclL[tid];
            if (tid == 64) offsD[i * 64 + 64] = exclL[64];
            for (int e = segB + tid; e < segE; e += 256) {
                unsigned int r = rtmp[e];
                int d = (int)(r & 63u);
                int rank = atomicAdd(&cur2[d], 1);       // LDS atomic
                recs[exclL[d] + rank] = r >> 6;
            }
        }
        return;
    }

    // ---- phaseA pipeline (r9 structure, range-parametrized) ----
    int paBid = (int)blockIdx.x - auxN;
    int paStride = (int)gridDim.x - auxN;

    if (tid < 17) sRB[tid] = relB[tid];
    __syncthreads();
    int rtot = sRB[16];

    int row = tid >> 2, c0 = tid & 3;

    auto tileInfo = [&](int vb, int& trow0, int& tr) -> bool {
        int chunk = vb / 136;
        int lane = vb - chunk * 136;
        int r = lane >> 3;
        int i = chunk * 8 + (lane & 7);
        int base, cnt;
        if (r == 16) { base = rtot; cnt = N_PAD / 64; }
        else         { base = sRB[r]; cnt = (sRB[r + 1] - base) >> 6; }
        if (i >= cnt) return false;
        trow0 = base + i * 64; tr = r;
        return true;
    };

    int vb = vb0 + paBid;
    int cur_row0, cur_r;
    while (vb < vb1 && !tileInfo(vb, cur_row0, cur_r)) vb += paStride;
    if (vb >= vb1) return;                      // uniform whole-block exit

    uint4 g0, g1, g2, g3;
    {
        int sr = (cur_r == 16) ? (cur_row0 - rtot + row) : srcOf[cur_row0 + row];
        const uint4* xp = (const uint4*)(x + (size_t)sr * DIM);
        g0 = xp[c0]; g1 = xp[c0 + 4]; g2 = xp[c0 + 8]; g3 = xp[c0 + 12];
    }

    int w = tid >> 6, l = tid & 63;
    int nl = l & 15, q = l >> 4;

    while (true) {
        {
            uint4* lp = (uint4*)(&Xs[row * 136]);
            lp[c0] = g0; lp[c0 + 4] = g1; lp[c0 + 8] = g2; lp[c0 + 12] = g3;
        }
        bf16x8 Bf[2][4];
        {
            const unsigned short* wr = Wb + cur_r * 16384;
            #pragma unroll
            for (int nt = 0; nt < 2; ++nt) {
                int n = w * 32 + nt * 16 + nl;
                #pragma unroll
                for (int kc = 0; kc < 4; ++kc)
                    Bf[nt][kc] = *(const bf16x8*)(wr + n * 128 + kc * 32 + q * 8);
            }
        }
        int nvb = vb + paStride;
        int nxt_row0 = 0, nxt_r = 0;
        while (nvb < vb1 && !tileInfo(nvb, nxt_row0, nxt_r)) nvb += paStride;
        bool nhave = (nvb < vb1);
        if (nhave) {
            int sr = (nxt_r == 16) ? (nxt_row0 - rtot + row) : srcOf[nxt_row0 + row];
            const uint4* xp = (const uint4*)(x + (size_t)sr * DIM);
            g0 = xp[c0]; g1 = xp[c0 + 4]; g2 = xp[c0 + 8]; g3 = xp[c0 + 12];
        }
        __syncthreads();
        #pragma unroll
        for (int m = 0; m < 4; ++m) {
            f32x4 a0 = {0.f, 0.f, 0.f, 0.f}, a1 = {0.f, 0.f, 0.f, 0.f};
            #pragma unroll
            for (int kc = 0; kc < 4; ++kc) {
                bf16x8 a = *(const bf16x8*)(&Xs[(m * 16 + nl) * 136 + kc * 32 + q * 8]);
                a0 = __builtin_amdgcn_mfma_f32_16x16x32_bf16(a, Bf[0][kc], a0, 0, 0, 0);
                a1 = __builtin_amdgcn_mfma_f32_16x16x32_bf16(a, Bf[1][kc], a1, 0, 0, 0);
            }
            int colb = w * 32 + nl;
            #pragma unroll
            for (int reg = 0; reg < 4; ++reg) {
                int row2 = m * 16 + q * 4 + reg;
                int sw = ((row2 >> 3) & 1) << 4;
                Cs[row2 * 136 + (colb ^ sw)]        = f2bf(a0[reg]);
                Cs[row2 * 136 + ((colb + 16) ^ sw)] = f2bf(a1[reg]);
            }
        }
        __syncthreads();
        {
            unsigned short* Tb = T + (size_t)cur_row0 * DIM;
            #pragma unroll
            for (int it = 0; it < 4; ++it) {
                int c = tid + it * 256;
                int rw = c >> 4, k8 = c & 15;
                int sw = ((rw >> 3) & 1) << 4;
                uint4 vv = *(const uint4*)(&Cs[rw * 136 + ((k8 * 8) ^ sw)]);
                *(uint4*)(Tb + rw * DIM + k8 * 8) = vv;
            }
        }
        if (!nhave) break;
        vb = nvb; cur_row0 = nxt_row0; cur_r = nxt_r;
    }
}

// ---- Phase B: gather-reduce over T. pool=0: write x2 with relu (layer 1).
// pool=1 (layer 2): relu'd rows staged to f32 LDS tile, segmented-reduced
// per graph, atomically added into hg_sum.
__global__ __launch_bounds__(256) void k_phaseB(
    const unsigned short* __restrict__ T, const unsigned int* __restrict__ recs,
    const int* __restrict__ offsD, const int* __restrict__ relB,
    const float* __restrict__ bias,
    unsigned short* __restrict__ aggOut,
    const int* __restrict__ gids, float* __restrict__ hg_sum, int pool)
{
    __shared__ int sOffs[33];
    __shared__ float sBias[128];
    __shared__ int sSelf;
    __shared__ float Sp[32][129];
    __shared__ int sGid[32];
    int tid = threadIdx.x;
    int v0 = blockIdx.x * 32;
    if (tid < 33) sOffs[tid] = offsD[v0 + tid];
    if (tid == 40) sSelf = relB[16];
    if (tid >= 64 && tid < 96) ((float4*)sBias)[tid - 64] = ((const float4*)bias)[tid - 64];
    if (pool && tid < 32) sGid[tid] = (v0 + tid < N_NODES) ? gids[v0 + tid] : -1;
    __syncthreads();

    int g = tid >> 3, s = tid & 7;
    int dst = v0 + g;
    float qa[16];
    #pragma unroll
    for (int i = 0; i < 16; ++i) qa[i] = sBias[s * 16 + i];

    int beg = sOffs[g], end = sOffs[g + 1];
    int e = beg;
    for (; e + 3 < end; e += 4) {
        unsigned int c0 = recs[e], c1 = recs[e+1], c2 = recs[e+2], c3 = recs[e+3];
        const uint4* t0 = (const uint4*)(T + (size_t)c0 * DIM + s * 16);
        const uint4* t1 = (const uint4*)(T + (size_t)c1 * DIM + s * 16);
        const uint4* t2 = (const uint4*)(T + (size_t)c2 * DIM + s * 16);
        const uint4* t3 = (const uint4*)(T + (size_t)c3 * DIM + s * 16);
        uint4 a0 = t0[0], a1 = t0[1], b0 = t1[0], b1 = t1[1];
        uint4 cc0 = t2[0], cc1 = t2[1], d0 = t3[0], d1 = t3[1];
        accum8(qa, a0); accum8(qa + 8, a1);
        accum8(qa, b0); accum8(qa + 8, b1);
        accum8(qa, cc0); accum8(qa + 8, cc1);
        accum8(qa, d0); accum8(qa + 8, d1);
    }
    for (; e < end; ++e) {
        unsigned int c = recs[e];
        const uint4* tp = (const uint4*)(T + (size_t)c * DIM + s * 16);
        uint4 u0 = tp[0], u1 = tp[1];
        accum8(qa, u0); accum8(qa + 8, u1);
    }
    {
        const uint4* tp = (const uint4*)(T + (size_t)(sSelf + dst) * DIM + s * 16);
        uint4 u0 = tp[0], u1 = tp[1];
        accum8(qa, u0); accum8(qa + 8, u1);
    }

    if (!pool) {
        #pragma unroll
        for (int i = 0; i < 16; ++i) qa[i] = fmaxf(qa[i], 0.f);
        pack16(qa, aggOut + (size_t)dst * DIM + s * 16);
    } else {
        #pragma unroll
        for (int i = 0; i < 16; ++i) Sp[g][s * 16 + i] = fmaxf(qa[i], 0.f);
        __syncthreads();
        // segmented reduce: 128 dims x 2 row-halves
        int d = tid & 127, hh = tid >> 7;
        float run = 0.f; int curg = -2;
        for (int n = hh * 16; n < hh * 16 + 16; ++n) {
            int g2 = sGid[n];
            if (g2 != curg) {
                if (curg >= 0) atomAddF(&hg_sum[curg * DIM + d], run);
                run = 0.f; curg = g2;
            }
            run += Sp[n][d];
        }
        if (curg >= 0) atomAddF(&hg_sum[curg * DIM + d], run);
    }
}

__global__ __launch_bounds__(256) void k_head(
    const float* __restrict__ hg_sum, const int* __restrict__ gids,
    const float* __restrict__ Wfc, const float* __restrict__ bfc,
    const float* __restrict__ Wc, const float* __restrict__ bc,
    float* __restrict__ out)
{
    int g = blockIdx.x, t = threadIdx.x;
    __shared__ float hgl[DIM];
    __shared__ float fcl[FC_DIM];
    __shared__ float lg[N_CLASSES];
    __shared__ int scnt;
    if (t == 0) {
        int lo = 0, hi = N_NODES;
        while (lo < hi) { int mid = (lo + hi) >> 1; if (gids[mid] < g) lo = mid + 1; else hi = mid; }
        int lb = lo;
        hi = N_NODES;
        while (lo < hi) { int mid = (lo + hi) >> 1; if (gids[mid] <= g) lo = mid + 1; else hi = mid; }
        scnt = lo - lb;
    }
    __syncthreads();
    if (t < DIM) {
        float c = (float)max(scnt, 1);
        hgl[t] = hg_sum[g*DIM + t] / c;
    }
    __syncthreads();
    {
        float sv = bfc[t];
        #pragma unroll 4
        for (int k = 0; k < DIM; ++k) sv += hgl[k] * Wfc[k*FC_DIM + t];
        fcl[t] = fmaxf(sv, 0.f);
    }
    __syncthreads();
    if (t < N_CLASSES) {
        float lgt = bc[t];
        #pragma unroll 4
        for (int k = 0; k < FC_DIM; ++k) lgt += fcl[k] * Wc[k*N_CLASSES + t];
        lg[t] = lgt;
    }
    __syncthreads();
    if (t < N_CLASSES) {
        float m = lg[0];
        #pragma unroll
        for (int c = 1; c < N_CLASSES; ++c) m = fmaxf(m, lg[c]);
        float sden = 0.f;
        #pragma unroll
        for (int c = 0; c < N_CLASSES; ++c) sden += expf(lg[c] - m);
        out[g*N_CLASSES + t] = expf(lg[t] - m) / sden;
    }
}

extern "C" void kernel_launch(void* const* d_in, const int* in_sizes, int n_in,
                              void* d_out, int out_size, void* d_ws, size_t ws_size,
                              hipStream_t stream)
{
    const float* h   = (const float*)d_in[0];
    const int*   src = (const int*)d_in[1];
    const int*   dst = (const int*)d_in[2];
    const int*   rel = (const int*)d_in[3];
    const int*   gid = (const int*)d_in[4];
    const float* W1  = (const float*)d_in[5];
    const float* Ws1 = (const float*)d_in[6];
    const float* b1  = (const float*)d_in[7];
    const float* W2  = (const float*)d_in[8];
    const float* Ws2 = (const float*)d_in[9];
    const float* b2  = (const float*)d_in[10];
    const float* Wfc = (const float*)d_in[11];
    const float* bfc = (const float*)d_in[12];
    const float* Wc  = (const float*)d_in[13];
    const float* bc  = (const float*)d_in[14];
    float* out = (float*)d_out;

    char* ws = (char*)d_ws;
    unsigned char* mark = (unsigned char*)(ws + WS_MARK);
    float* hgsum = (float*)(ws + WS_HG);
    int*   srcOf = (int*)(ws + WS_SRCOF);
    int*   blkH  = (int*)(ws + WS_BLKH);
    int*   cOffs = (int*)(ws + WS_COFS);
    int*   partP = (int*)(ws + WS_PARTP);
    int*   blkB  = (int*)(ws + WS_BLKB);
    int*   relB  = (int*)(ws + WS_RELB);
    int*   cidMap= (int*)(ws + WS_CIDMAP);
    unsigned int* rtmp = (unsigned int*)(ws + WS_RTMP);
    unsigned int* recs = (unsigned int*)(ws + WS_RECS);
    int*   offsD = (int*)(ws + WS_OFFSD);
    unsigned short* x1  = (unsigned short*)(ws + WS_X1);
    unsigned short* x2  = (unsigned short*)(ws + WS_X2);
    unsigned short* Wb  = (unsigned short*)(ws + WS_WB);
    unsigned short* T   = (unsigned short*)(ws + WS_T);

    hipMemsetAsync(mark, 0, MEMSET_SZ, stream);    // mark+hg+srcOf

    k_h1cx<<<NCH + NBLK_CX, 256, 0, stream>>>(src, dst, rel, mark, blkH,
                                              h, x1, W1, Ws1, W2, Ws2, Wb);
    k_sA<<<NBLK_PP + NCOARSE, 256, 0, stream>>>((const unsigned int*)mark, partP,
                                                blkH, cOffs);
    k_sB<<<2, 1024, 0, stream>>>(partP, blkB, relB, cOffs);
    k_scanPC<<<NBLK_PP, 256, 0, stream>>>((const unsigned int*)mark, blkB, cidMap, srcOf);

    // phaseA1 half 1 overlapped with scat1; half 2 overlapped with p2.
    k_fuseAP<<<NCH + PA_BLK, 256, 0, stream>>>(x1, Wb, srcOf, relB, T,
                                               src, dst, rel, cidMap, blkH, cOffs,
                                               rtmp, recs, offsD,
                                               1, NCH, 0, VB_SPLIT);
    k_fuseAP<<<NCOARSE + PA_BLK, 256, 0, stream>>>(x1, Wb, srcOf, relB, T,
                                                   src, dst, rel, cidMap, blkH, cOffs,
                                                   rtmp, recs, offsD,
                                                   2, NCOARSE, VB_SPLIT, NBVIRT);
    k_phaseB<<<N_PAD / 32, 256, 0, stream>>>(T, recs, offsD, relB, b1, x2, gid, hgsum, 0);
    k_fuseAP<<<PA_BLK, 256, 0, stream>>>(x2, Wb + 17 * 16384, srcOf, relB, T,
                                         src, dst, rel, cidMap, blkH, cOffs,
                                         rtmp, recs, offsD,
                                         0, 0, 0, NBVIRT);
    k_phaseB<<<N_PAD / 32, 256, 0, stream>>>(T, recs, offsD, relB, b2, x2, gid, hgsum, 1);

    k_head<<<N_GRAPHS, 256, 0, stream>>>(hgsum, gid, Wfc, bfc, Wc, bc, out);
}

// Round 11
// 375.358 us; speedup vs baseline: 1.0187x; 1.0187x over previous
//
#include <hip/hip_runtime.h>
#include <hip/hip_bf16.h>

#define N_NODES   50000
#define N_PAD     50048                 // ceil64
#define N_EDGES   800000
#define N_REL     16
#define N_GRAPHS  64
#define DIM       128
#define FC_DIM    256
#define N_CLASSES 16

#define SB        50176                 // src bins per rel (49*1024)
#define NBINS_P   (16 * SB)             // 802816
#define NBLK_PP   784
#define NCOARSE   782                   // dst>>6 bins
#define NCH       392                   // edge chunks
#define CHSZ      2048
// virtual blocks for phase A: fixed internal sweep chunking (independent of NCH)
#define NBVIRT    13328
#define GRID_A    1024                  // 4 blocks/CU resident; grid-stride + pipeline

#define NBLK_CX   27200                 // XW_TOTAL/256
#define XW_TOTAL  (N_PAD * DIM + 2 * 17 * 16384)

// ---- ws layout (bytes, 256-aligned) ----
#define WS_MARK   0                     // 802816  } contiguous
#define WS_HG     802816                // 32768   } memset
#define WS_CNT    835584                // 256     } region (hole, unused)
#define WS_SRCOF  835840                // 3203072 } (pads must be 0)
#define MEMSET_SZ 4038912
#define WS_BLKH   4038912               // 392*782*4 = 1226176 -> 1226240
#define WS_COFS   5265152               // 3328
#define WS_PARTP  5268480               // 3328
#define WS_BLKB   5271808               // 3328
#define WS_RELB   5275136               // 256
#define WS_CIDMAP 5275392               // 3211264
#define WS_RTMP   8486656               // 3200000
#define WS_RECS   11686656              // 3200000
#define WS_OFFSD  14886656              // 200448
#define WS_X1     15087104              // 12812288
#define WS_X2     27899392              // 12812288
#define WS_WB     40711680              // 1114112
#define WS_T      41825792              // + rows*256B (actual ~143MB)

typedef __attribute__((ext_vector_type(8))) short bf16x8;
typedef __attribute__((ext_vector_type(4))) float f32x4;

__device__ __forceinline__ void atomAddF(float* p, float v) {
#if defined(__gfx90a__) || defined(__gfx942__) || defined(__gfx950__)
    unsafeAtomicAdd(p, v);
#else
    atomicAdd(p, v);
#endif
}

__device__ __forceinline__ float bf2f(unsigned int u) {
    union { float f; unsigned int i; } x; x.i = u << 16; return x.f;
}
__device__ __forceinline__ unsigned short f2bf(float f) {
    union { float f; unsigned int u; } x; x.f = f;
    unsigned int r = x.u + 0x7fff + ((x.u >> 16) & 1);
    return (unsigned short)(r >> 16);
}
__device__ __forceinline__ void accum8(float* qa, uint4 u) {
    qa[0] += bf2f(u.x & 0xffff); qa[1] += bf2f(u.x >> 16);
    qa[2] += bf2f(u.y & 0xffff); qa[3] += bf2f(u.y >> 16);
    qa[4] += bf2f(u.z & 0xffff); qa[5] += bf2f(u.z >> 16);
    qa[6] += bf2f(u.w & 0xffff); qa[7] += bf2f(u.w >> 16);
}
__device__ __forceinline__ void pack16(const float* qa, unsigned short* dst) {
    #pragma unroll
    for (int j = 0; j < 2; ++j) {
        uint4 w;
        w.x = ((unsigned int)f2bf(qa[j*8+1]) << 16) | f2bf(qa[j*8+0]);
        w.y = ((unsigned int)f2bf(qa[j*8+3]) << 16) | f2bf(qa[j*8+2]);
        w.z = ((unsigned int)f2bf(qa[j*8+5]) << 16) | f2bf(qa[j*8+4]);
        w.w = ((unsigned int)f2bf(qa[j*8+7]) << 16) | f2bf(qa[j*8+6]);
        ((uint4*)dst)[j] = w;
    }
}

// ---- fused: h1 (blocks 0..391, runs first) + convXW (blocks 392..) ----
__global__ __launch_bounds__(256) void k_h1cx(
    const int* __restrict__ src, const int* __restrict__ dst, const int* __restrict__ rel,
    unsigned char* __restrict__ mark, int* __restrict__ blockHist,
    const float* __restrict__ h, unsigned short* __restrict__ x1,
    const float* __restrict__ W1, const float* __restrict__ Ws1,
    const float* __restrict__ W2, const float* __restrict__ Ws2,
    unsigned short* __restrict__ Wb)
{
    __shared__ int hl[NCOARSE];
    int t = threadIdx.x;
    if (blockIdx.x < NCH) {
        int b = blockIdx.x;
        for (int i = t; i < NCOARSE; i += 256) hl[i] = 0;
        __syncthreads();
        int e0 = b * CHSZ;
        int eend = min(e0 + CHSZ, N_EDGES);
        for (int e = e0 + t; e < eend; e += 256) {
            int d = dst[e];
            mark[rel[e] * SB + src[e]] = 1;
            atomicAdd(&hl[d >> 6], 1);                   // LDS atomic
        }
        __syncthreads();
        for (int i = t; i < NCOARSE; i += 256) blockHist[b * NCOARSE + i] = hl[i];
    } else {
        int id = (blockIdx.x - NCH) * 256 + t;
        if (id < N_PAD * DIM) {
            int v = id >> 7;
            x1[id] = (v < N_NODES) ? f2bf(h[id]) : (unsigned short)0;
        } else {
            int tt = id - N_PAD * DIM;
            int l = tt / 278528, rem = tt % 278528;
            int r = rem >> 14, rr = rem & 16383;
            int n = rr >> 7, k = rr & 127;
            const float* W  = l ? W2 : W1;
            const float* Ws = l ? Ws2 : Ws1;
            float v = (r < 16) ? W[r * 16384 + k * 128 + n] : Ws[k * 128 + n];
            Wb[tt] = f2bf(v);
        }
    }
}

// ---- fused: scanPA (blocks 0..783) + per-bin chunk scan (blocks 784..1565).
__global__ __launch_bounds__(256) void k_sA(
    const unsigned int* __restrict__ markU, int* __restrict__ partP,
    int* __restrict__ blockHist, int* __restrict__ cOffs)
{
    int t = threadIdx.x;
    if (blockIdx.x < NBLK_PP) {
        __shared__ int red[256];
        int b = blockIdx.x;
        unsigned int u = markU[b * 256 + t];
        red[t] = (int)((u & 1) + ((u >> 8) & 1) + ((u >> 16) & 1) + ((u >> 24) & 1));
        __syncthreads();
        for (int o = 128; o > 0; o >>= 1) {
            if (t < o) red[t] += red[t + o];
            __syncthreads();
        }
        if (t == 0) partP[b] = red[0];
    } else {
        __shared__ int sc[2][256];
        int i = blockIdx.x - NBLK_PP;                    // 0..781
        int j0 = 2 * t, j1 = 2 * t + 1;
        int v0 = (j0 < NCH) ? blockHist[j0 * NCOARSE + i] : 0;
        int v1 = (j1 < NCH) ? blockHist[j1 * NCOARSE + i] : 0;
        int p = v0 + v1;
        sc[0][t] = p; __syncthreads();
        int cur = 0;
        for (int o = 1; o < 256; o <<= 1) {
            sc[cur ^ 1][t] = sc[cur][t] + ((t >= o) ? sc[cur][t - o] : 0);
            __syncthreads();
            cur ^= 1;
        }
        int excl = sc[cur][t] - p;                       // exclusive, no base
        if (j0 < NCH) blockHist[j0 * NCOARSE + i] = excl;
        if (j1 < NCH) blockHist[j1 * NCOARSE + i] = excl + v0;
        if (t == 255) cOffs[i] = sc[cur][255];           // bin total
    }
}

// ---- fused: scanPB (block 0) + cscanB (block 1) ----
__global__ __launch_bounds__(1024) void k_sB(
    const int* __restrict__ partP, int* __restrict__ blkB, int* __restrict__ relB,
    int* __restrict__ cOffs)
{
    int t = threadIdx.x;
    if (blockIdx.x == 0) {
        __shared__ int s1[784], s2[784];
        __shared__ int tot[16], rbase[17];
        int rel = t / 49, pos = t - rel * 49;
        int v = (t < 784) ? partP[t] : 0;
        if (t < 784) s1[t] = v;
        __syncthreads();
        int* cur = s1; int* nxt = s2;
        for (int o = 1; o < 64; o <<= 1) {
            if (t < 784) nxt[t] = cur[t] + ((pos >= o) ? cur[t - o] : 0);
            __syncthreads();
            int* tmp = cur; cur = nxt; nxt = tmp;
        }
        if (t < 784 && pos == 48) tot[rel] = cur[t];
        __syncthreads();
        if (t == 0) {
            int base = 0;
            for (int r = 0; r < 16; ++r) { rbase[r] = base; base += (tot[r] + 63) & ~63; }
            rbase[16] = base;
        }
        __syncthreads();
        if (t < 784) blkB[t] = rbase[rel] + cur[t] - v;
        if (t < 17)  relB[t] = rbase[t];
    } else {
        __shared__ int c1[1024], c2[1024];
        int v = (t < NCOARSE) ? cOffs[t] : 0;
        c1[t] = v; __syncthreads();
        int* cur = c1; int* nxt = c2;
        for (int o = 1; o < 1024; o <<= 1) {
            nxt[t] = cur[t] + ((t >= o) ? cur[t - o] : 0);
            __syncthreads();
            int* tmp = cur; cur = nxt; nxt = tmp;
        }
        if (t < NCOARSE) cOffs[t] = cur[t] - v;          // exclusive base
        if (t == NCOARSE) cOffs[NCOARSE] = cur[NCOARSE - 1];
    }
}

__global__ void k_scanPC(const unsigned int* __restrict__ markU, const int* __restrict__ blkB,
                         int* __restrict__ cidMap, int* __restrict__ srcOf) {
    __shared__ int s1[256], s2[256];
    int b = blockIdx.x, t = threadIdx.x;
    unsigned int u = markU[b * 256 + t];
    int f0 = (int)(u & 1), f1 = (int)((u >> 8) & 1);
    int f2 = (int)((u >> 16) & 1), f3 = (int)((u >> 24) & 1);
    int sum = f0 + f1 + f2 + f3;
    s1[t] = sum; __syncthreads();
    int* cur = s1; int* nxt = s2;
    for (int o = 1; o < 256; o <<= 1) {
        nxt[t] = cur[t] + ((t >= o) ? cur[t - o] : 0);
        __syncthreads();
        int* tmp = cur; cur = nxt; nxt = tmp;
    }
    int cid = blkB[b] + cur[t] - sum;
    int rel = b / 49;
    int key0 = b * 1024 + t * 4;
    int srcBase = key0 - rel * SB;
    if (f0) { cidMap[key0]     = cid; srcOf[cid] = srcBase;     cid++; }
    if (f1) { cidMap[key0 + 1] = cid; srcOf[cid] = srcBase + 1; cid++; }
    if (f2) { cidMap[key0 + 2] = cid; srcOf[cid] = srcBase + 2; cid++; }
    if (f3) { cidMap[key0 + 3] = cid; srcOf[cid] = srcBase + 3; cid++; }
}

// ---- sort pass 1b: scatter to coarse segments ----
__global__ __launch_bounds__(256) void k_scat1(
    const int* __restrict__ src, const int* __restrict__ dst, const int* __restrict__ rel,
    const int* __restrict__ cidMap, const int* __restrict__ blockHist,
    const int* __restrict__ cOffs, unsigned int* __restrict__ rtmp)
{
    __shared__ int baseL[NCOARSE];
    __shared__ int hl[NCOARSE];
    int b = blockIdx.x, t = threadIdx.x;
    for (int i = t; i < NCOARSE; i += 256) {
        baseL[i] = blockHist[b * NCOARSE + i] + cOffs[i];
        hl[i] = 0;
    }
    __syncthreads();
    int e0 = b * CHSZ;
    int eend = min(e0 + CHSZ, N_EDGES);
    for (int e = e0 + t; e < eend; e += 256) {
        int d = dst[e];
        int cid = cidMap[rel[e] * SB + src[e]];
        int c = d >> 6;
        int rank = atomicAdd(&hl[c], 1);                 // LDS atomic
        rtmp[baseL[c] + rank] = ((unsigned int)cid << 6) | (unsigned int)(d & 63);
    }
}

// ---- sort pass 2: per coarse bin, final 64-way local sort + offsD ----
__global__ __launch_bounds__(256) void k_p2(
    const unsigned int* __restrict__ rtmp, const int* __restrict__ coarseOffs,
    unsigned int* __restrict__ recs, int* __restrict__ offsD)
{
    __shared__ int cntL[64], exclL[65], cur2[64];
    int i = blockIdx.x, t = threadIdx.x;
    int segB = coarseOffs[i], segE = coarseOffs[i + 1];
    if (t < 64) { cntL[t] = 0; cur2[t] = 0; }
    __syncthreads();
    for (int e = segB + t; e < segE; e += 256)
        atomicAdd(&cntL[rtmp[e] & 63u], 1);
    __syncthreads();
    if (t == 0) {
        int run = segB;
        #pragma unroll
        for (int d = 0; d < 64; ++d) { exclL[d] = run; run += cntL[d]; }
        exclL[64] = run;
    }
    __syncthreads();
    if (t < 64) offsD[i * 64 + t] = exclL[t];
    if (t == 64) offsD[i * 64 + 64] = exclL[64];
    for (int e = segB + t; e < segE; e += 256) {
        unsigned int r = rtmp[e];
        int d = (int)(r & 63u);
        int rank = atomicAdd(&cur2[d], 1);               // LDS atomic
        recs[exclL[d] + rank] = r >> 6;
    }
}

// ---- Phase A: gather-GEMM over compact rows (unchanged r9) ----
__global__ __launch_bounds__(256) void k_phaseA(
    const unsigned short* __restrict__ x, const unsigned short* __restrict__ Wb,
    const int* __restrict__ srcOf, const int* __restrict__ relB,
    unsigned short* __restrict__ T)
{
    __shared__ __attribute__((aligned(16))) unsigned short Xs[64 * 136];
    __shared__ __attribute__((aligned(16))) unsigned short Cs[64 * 136];
    __shared__ int sRB[17];

    int tid = threadIdx.x;
    if (tid < 17) sRB[tid] = relB[tid];
    __syncthreads();
    int rtot = sRB[16];

    int row = tid >> 2, c0 = tid & 3;

    auto tileInfo = [&](int vb, int& trow0, int& tr) -> bool {
        int chunk = vb / 136;
        int lane = vb - chunk * 136;
        int r = lane >> 3;
        int i = chunk * 8 + (lane & 7);
        int base, cnt;
        if (r == 16) { base = rtot; cnt = N_PAD / 64; }
        else         { base = sRB[r]; cnt = (sRB[r + 1] - base) >> 6; }
        if (i >= cnt) return false;
        trow0 = base + i * 64; tr = r;
        return true;
    };

    int vb = blockIdx.x;
    int cur_row0, cur_r;
    while (vb < NBVIRT && !tileInfo(vb, cur_row0, cur_r)) vb += gridDim.x;
    if (vb >= NBVIRT) return;

    uint4 g0, g1, g2, g3;
    {
        int sr = (cur_r == 16) ? (cur_row0 - rtot + row) : srcOf[cur_row0 + row];
        const uint4* xp = (const uint4*)(x + (size_t)sr * DIM);
        g0 = xp[c0]; g1 = xp[c0 + 4]; g2 = xp[c0 + 8]; g3 = xp[c0 + 12];
    }

    int w = tid >> 6, l = tid & 63;
    int nl = l & 15, q = l >> 4;

    while (true) {
        {
            uint4* lp = (uint4*)(&Xs[row * 136]);
            lp[c0] = g0; lp[c0 + 4] = g1; lp[c0 + 8] = g2; lp[c0 + 12] = g3;
        }
        bf16x8 Bf[2][4];
        {
            const unsigned short* wr = Wb + cur_r * 16384;
            #pragma unroll
            for (int nt = 0; nt < 2; ++nt) {
                int n = w * 32 + nt * 16 + nl;
                #pragma unroll
                for (int kc = 0; kc < 4; ++kc)
                    Bf[nt][kc] = *(const bf16x8*)(wr + n * 128 + kc * 32 + q * 8);
            }
        }
        int nvb = vb + gridDim.x;
        int nxt_row0 = 0, nxt_r = 0;
        while (nvb < NBVIRT && !tileInfo(nvb, nxt_row0, nxt_r)) nvb += gridDim.x;
        bool nhave = (nvb < NBVIRT);
        if (nhave) {
            int sr = (nxt_r == 16) ? (nxt_row0 - rtot + row) : srcOf[nxt_row0 + row];
            const uint4* xp = (const uint4*)(x + (size_t)sr * DIM);
            g0 = xp[c0]; g1 = xp[c0 + 4]; g2 = xp[c0 + 8]; g3 = xp[c0 + 12];
        }
        __syncthreads();
        #pragma unroll
        for (int m = 0; m < 4; ++m) {
            f32x4 a0 = {0.f, 0.f, 0.f, 0.f}, a1 = {0.f, 0.f, 0.f, 0.f};
            #pragma unroll
            for (int kc = 0; kc < 4; ++kc) {
                bf16x8 a = *(const bf16x8*)(&Xs[(m * 16 + nl) * 136 + kc * 32 + q * 8]);
                a0 = __builtin_amdgcn_mfma_f32_16x16x32_bf16(a, Bf[0][kc], a0, 0, 0, 0);
                a1 = __builtin_amdgcn_mfma_f32_16x16x32_bf16(a, Bf[1][kc], a1, 0, 0, 0);
            }
            int colb = w * 32 + nl;
            #pragma unroll
            for (int reg = 0; reg < 4; ++reg) {
                int row2 = m * 16 + q * 4 + reg;
                int sw = ((row2 >> 3) & 1) << 4;
                Cs[row2 * 136 + (colb ^ sw)]        = f2bf(a0[reg]);
                Cs[row2 * 136 + ((colb + 16) ^ sw)] = f2bf(a1[reg]);
            }
        }
        __syncthreads();
        {
            unsigned short* Tb = T + (size_t)cur_row0 * DIM;
            #pragma unroll
            for (int it = 0; it < 4; ++it) {
                int c = tid + it * 256;
                int rw = c >> 4, k8 = c & 15;
                int sw = ((rw >> 3) & 1) << 4;
                uint4 vv = *(const uint4*)(&Cs[rw * 136 + ((k8 * 8) ^ sw)]);
                *(uint4*)(Tb + rw * DIM + k8 * 8) = vv;
            }
        }
        if (!nhave) break;
        vb = nvb; cur_row0 = nxt_row0; cur_r = nxt_r;
    }
}

// ---- Phase B: gather-reduce over T. r11: 8-deep batched gather (16 uint4
// in flight) to halve serial latency windows; accumulation order unchanged
// (strictly edge-ordered -> bitwise-identical result).
// pool=0: write x2 with relu. pool=1: fused mean-pool via LDS stage +
// segmented reduce + global atomics.
__global__ __launch_bounds__(256) void k_phaseB(
    const unsigned short* __restrict__ T, const unsigned int* __restrict__ recs,
    const int* __restrict__ offsD, const int* __restrict__ relB,
    const float* __restrict__ bias,
    unsigned short* __restrict__ aggOut,
    const int* __restrict__ gids, float* __restrict__ hg_sum, int pool)
{
    __shared__ int sOffs[33];
    __shared__ float sBias[128];
    __shared__ int sSelf;
    __shared__ float Sp[32][129];
    __shared__ int sGid[32];
    int tid = threadIdx.x;
    int v0 = blockIdx.x * 32;
    if (tid < 33) sOffs[tid] = offsD[v0 + tid];
    if (tid == 40) sSelf = relB[16];
    if (tid >= 64 && tid < 96) ((float4*)sBias)[tid - 64] = ((const float4*)bias)[tid - 64];
    if (pool && tid < 32) sGid[tid] = (v0 + tid < N_NODES) ? gids[v0 + tid] : -1;
    __syncthreads();

    int g = tid >> 3, s = tid & 7;
    int dst = v0 + g;
    float qa[16];
    #pragma unroll
    for (int i = 0; i < 16; ++i) qa[i] = sBias[s * 16 + i];

    int beg = sOffs[g], end = sOffs[g + 1];
    int e = beg;
    for (; e + 7 < end; e += 8) {        // 8-deep: 16 row-loads in flight
        unsigned int c0 = recs[e],   c1 = recs[e+1], c2 = recs[e+2], c3 = recs[e+3];
        unsigned int c4 = recs[e+4], c5 = recs[e+5], c6 = recs[e+6], c7 = recs[e+7];
        const uint4* t0 = (const uint4*)(T + (size_t)c0 * DIM + s * 16);
        const uint4* t1 = (const uint4*)(T + (size_t)c1 * DIM + s * 16);
        const uint4* t2 = (const uint4*)(T + (size_t)c2 * DIM + s * 16);
        const uint4* t3 = (const uint4*)(T + (size_t)c3 * DIM + s * 16);
        const uint4* t4 = (const uint4*)(T + (size_t)c4 * DIM + s * 16);
        const uint4* t5 = (const uint4*)(T + (size_t)c5 * DIM + s * 16);
        const uint4* t6 = (const uint4*)(T + (size_t)c6 * DIM + s * 16);
        const uint4* t7 = (const uint4*)(T + (size_t)c7 * DIM + s * 16);
        uint4 a0 = t0[0], a1 = t0[1], b0 = t1[0], b1 = t1[1];
        uint4 d0 = t2[0], d1 = t2[1], e0 = t3[0], e1 = t3[1];
        uint4 f0 = t4[0], f1 = t4[1], h0 = t5[0], h1 = t5[1];
        uint4 i0 = t6[0], i1 = t6[1], j0 = t7[0], j1 = t7[1];
        accum8(qa, a0); accum8(qa + 8, a1);
        accum8(qa, b0); accum8(qa + 8, b1);
        accum8(qa, d0); accum8(qa + 8, d1);
        accum8(qa, e0); accum8(qa + 8, e1);
        accum8(qa, f0); accum8(qa + 8, f1);
        accum8(qa, h0); accum8(qa + 8, h1);
        accum8(qa, i0); accum8(qa + 8, i1);
        accum8(qa, j0); accum8(qa + 8, j1);
    }
    for (; e + 3 < end; e += 4) {
        unsigned int c0 = recs[e], c1 = recs[e+1], c2 = recs[e+2], c3 = recs[e+3];
        const uint4* t0 = (const uint4*)(T + (size_t)c0 * DIM + s * 16);
        const uint4* t1 = (const uint4*)(T + (size_t)c1 * DIM + s * 16);
        const uint4* t2 = (const uint4*)(T + (size_t)c2 * DIM + s * 16);
        const uint4* t3 = (const uint4*)(T + (size_t)c3 * DIM + s * 16);
        uint4 a0 = t0[0], a1 = t0[1], b0 = t1[0], b1 = t1[1];
        uint4 cc0 = t2[0], cc1 = t2[1], d0 = t3[0], d1 = t3[1];
        accum8(qa, a0); accum8(qa + 8, a1);
        accum8(qa, b0); accum8(qa + 8, b1);
        accum8(qa, cc0); accum8(qa + 8, cc1);
        accum8(qa, d0); accum8(qa + 8, d1);
    }
    for (; e < end; ++e) {
        unsigned int c = recs[e];
        const uint4* tp = (const uint4*)(T + (size_t)c * DIM + s * 16);
        uint4 u0 = tp[0], u1 = tp[1];
        accum8(qa, u0); accum8(qa + 8, u1);
    }
    {
        const uint4* tp = (const uint4*)(T + (size_t)(sSelf + dst) * DIM + s * 16);
        uint4 u0 = tp[0], u1 = tp[1];
        accum8(qa, u0); accum8(qa + 8, u1);
    }

    if (!pool) {
        #pragma unroll
        for (int i = 0; i < 16; ++i) qa[i] = fmaxf(qa[i], 0.f);
        pack16(qa, aggOut + (size_t)dst * DIM + s * 16);
    } else {
        #pragma unroll
        for (int i = 0; i < 16; ++i) Sp[g][s * 16 + i] = fmaxf(qa[i], 0.f);
        __syncthreads();
        // segmented reduce: 128 dims x 2 row-halves
        int d = tid & 127, hh = tid >> 7;
        float run = 0.f; int curg = -2;
        for (int n = hh * 16; n < hh * 16 + 16; ++n) {
            int g2 = sGid[n];
            if (g2 != curg) {
                if (curg >= 0) atomAddF(&hg_sum[curg * DIM + d], run);
                run = 0.f; curg = g2;
            }
            run += Sp[n][d];
        }
        if (curg >= 0) atomAddF(&hg_sum[curg * DIM + d], run);
    }
}

__global__ __launch_bounds__(256) void k_head(
    const float* __restrict__ hg_sum, const int* __restrict__ gids,
    const float* __restrict__ Wfc, const float* __restrict__ bfc,
    const float* __restrict__ Wc, const float* __restrict__ bc,
    float* __restrict__ out)
{
    int g = blockIdx.x, t = threadIdx.x;
    __shared__ float hgl[DIM];
    __shared__ float fcl[FC_DIM];
    __shared__ float lg[N_CLASSES];
    __shared__ int scnt;
    if (t == 0) {
        int lo = 0, hi = N_NODES;
        while (lo < hi) { int mid = (lo + hi) >> 1; if (gids[mid] < g) lo = mid + 1; else hi = mid; }
        int lb = lo;
        hi = N_NODES;
        while (lo < hi) { int mid = (lo + hi) >> 1; if (gids[mid] <= g) lo = mid + 1; else hi = mid; }
        scnt = lo - lb;
    }
    __syncthreads();
    if (t < DIM) {
        float c = (float)max(scnt, 1);
        hgl[t] = hg_sum[g*DIM + t] / c;
    }
    __syncthreads();
    {
        float sv = bfc[t];
        #pragma unroll 4
        for (int k = 0; k < DIM; ++k) sv += hgl[k] * Wfc[k*FC_DIM + t];
        fcl[t] = fmaxf(sv, 0.f);
    }
    __syncthreads();
    if (t < N_CLASSES) {
        float lgt = bc[t];
        #pragma unroll 4
        for (int k = 0; k < FC_DIM; ++k) lgt += fcl[k] * Wc[k*N_CLASSES + t];
        lg[t] = lgt;
    }
    __syncthreads();
    if (t < N_CLASSES) {
        float m = lg[0];
        #pragma unroll
        for (int c = 1; c < N_CLASSES; ++c) m = fmaxf(m, lg[c]);
        float sden = 0.f;
        #pragma unroll
        for (int c = 0; c < N_CLASSES; ++c) sden += expf(lg[c] - m);
        out[g*N_CLASSES + t] = expf(lg[t] - m) / sden;
    }
}

extern "C" void kernel_launch(void* const* d_in, const int* in_sizes, int n_in,
                              void* d_out, int out_size, void* d_ws, size_t ws_size,
                              hipStream_t stream)
{
    const float* h   = (const float*)d_in[0];
    const int*   src = (const int*)d_in[1];
    const int*   dst = (const int*)d_in[2];
    const int*   rel = (const int*)d_in[3];
    const int*   gid = (const int*)d_in[4];
    const float* W1  = (const float*)d_in[5];
    const float* Ws1 = (const float*)d_in[6];
    const float* b1  = (const float*)d_in[7];
    const float* W2  = (const float*)d_in[8];
    const float* Ws2 = (const float*)d_in[9];
    const float* b2  = (const float*)d_in[10];
    const float* Wfc = (const float*)d_in[11];
    const float* bfc = (const float*)d_in[12];
    const float* Wc  = (const float*)d_in[13];
    const float* bc  = (const float*)d_in[14];
    float* out = (float*)d_out;

    char* ws = (char*)d_ws;
    unsigned char* mark = (unsigned char*)(ws + WS_MARK);
    float* hgsum = (float*)(ws + WS_HG);
    int*   srcOf = (int*)(ws + WS_SRCOF);
    int*   blkH  = (int*)(ws + WS_BLKH);
    int*   cOffs = (int*)(ws + WS_COFS);
    int*   partP = (int*)(ws + WS_PARTP);
    int*   blkB  = (int*)(ws + WS_BLKB);
    int*   relB  = (int*)(ws + WS_RELB);
    int*   cidMap= (int*)(ws + WS_CIDMAP);
    unsigned int* rtmp = (unsigned int*)(ws + WS_RTMP);
    unsigned int* recs = (unsigned int*)(ws + WS_RECS);
    int*   offsD = (int*)(ws + WS_OFFSD);
    unsigned short* x1  = (unsigned short*)(ws + WS_X1);
    unsigned short* x2  = (unsigned short*)(ws + WS_X2);
    unsigned short* Wb  = (unsigned short*)(ws + WS_WB);
    unsigned short* T   = (unsigned short*)(ws + WS_T);

    hipMemsetAsync(mark, 0, MEMSET_SZ, stream);    // mark+hg+srcOf

    k_h1cx<<<NCH + NBLK_CX, 256, 0, stream>>>(src, dst, rel, mark, blkH,
                                              h, x1, W1, Ws1, W2, Ws2, Wb);
    k_sA<<<NBLK_PP + NCOARSE, 256, 0, stream>>>((const unsigned int*)mark, partP,
                                                blkH, cOffs);
    k_sB<<<2, 1024, 0, stream>>>(partP, blkB, relB, cOffs);
    k_scanPC<<<NBLK_PP, 256, 0, stream>>>((const unsigned int*)mark, blkB, cidMap, srcOf);

    k_scat1<<<NCH, 256, 0, stream>>>(src, dst, rel, cidMap, blkH, cOffs, rtmp);
    k_p2<<<NCOARSE, 256, 0, stream>>>(rtmp, cOffs, recs, offsD);

    k_phaseA<<<GRID_A, 256, 0, stream>>>(x1, Wb, srcOf, relB, T);
    k_phaseB<<<N_PAD / 32, 256, 0, stream>>>(T, recs, offsD, relB, b1, x2, gid, hgsum, 0);
    k_phaseA<<<GRID_A, 256, 0, stream>>>(x2, Wb + 17 * 16384, srcOf, relB, T);
    k_phaseB<<<N_PAD / 32, 256, 0, stream>>>(T, recs, offsD, relB, b2, x2, gid, hgsum, 1);

    k_head<<<N_GRAPHS, 256, 0, stream>>>(hgsum, gid, Wfc, bfc, Wc, bc, out);
}